// Round 1
// 809.195 us; speedup vs baseline: 1.0387x; 1.0387x over previous
//
#include <hip/hip_runtime.h>

#define VEC_DIM   300
#define VEC_F4    75          // 300 / 4
#define NUM_WORDS 100000
#define BATCH_N   4096
#define NUM_CTX   10
#define NUM_NOISE 26
#define TWORDS    32          // words per transpose block (100000 % 32 == 0)

// ---------------- Transpose O (300 x 100000) -> OT (100000 x 300) ----------
// float4 on BOTH global sides. Each block: 32 words x 300 dims.
// LDS tile[w][d], pitch 300 floats (1200 B = 75*16 -> every row 16B-aligned).
// Phase-1 LDS scatter has 4-way bank aliasing (stride 1200B == 16 banks) --
// accepted: LDS is not the bottleneck, global BW is.
__global__ __launch_bounds__(256) void transpose_kernel(
    const float* __restrict__ O,   // (300, 100000)
    float*       __restrict__ OT)  // (100000, 300)
{
    __shared__ float tile[TWORDS * VEC_DIM];   // 37.5 KB
    const int wBase = blockIdx.x * TWORDS;
    const int tid   = threadIdx.x;

    // Phase 1: read O rows coalesced (float4 along words), scatter into tile[w][d].
    // idx -> (d = idx>>3, c = idx&7): lanes 0..7 cover 128 contiguous bytes of row d.
    for (int idx = tid; idx < VEC_DIM * (TWORDS / 4); idx += 256) {
        const int d = idx >> 3;
        const int c = idx & 7;
        const float4 v = *reinterpret_cast<const float4*>(
            O + (size_t)d * NUM_WORDS + wBase + 4 * c);
        tile[(4 * c + 0) * VEC_DIM + d] = v.x;
        tile[(4 * c + 1) * VEC_DIM + d] = v.y;
        tile[(4 * c + 2) * VEC_DIM + d] = v.z;
        tile[(4 * c + 3) * VEC_DIM + d] = v.w;
    }
    __syncthreads();

    // Phase 2: write OT rows coalesced (float4 along dims) via ds_read_b128.
    for (int idx = tid; idx < TWORDS * VEC_F4; idx += 256) {
        const int w = idx / VEC_F4;
        const int c = idx - w * VEC_F4;
        const float4 v = *reinterpret_cast<const float4*>(tile + w * VEC_DIM + 4 * c);
        *reinterpret_cast<float4*>(OT + (size_t)(wBase + w) * VEC_DIM + 4 * c) = v;
    }
}

// ---------------- Score kernel: float4 gathers, x held in registers --------
__global__ __launch_bounds__(256) void pvdm_score_kernel(
    const int*   __restrict__ context_ids,   // (B, 10)
    const int*   __restrict__ doc_ids,       // (B,)
    const int*   __restrict__ tn_ids,        // (B, 26)
    const float* __restrict__ D,             // (500000, 300)
    const float* __restrict__ W,             // (100000, 300)
    const float* __restrict__ OT,            // (100000, 300)
    float*       __restrict__ out)           // (B, 26)
{
    __shared__ float4 xs4[VEC_F4];
    const int b   = blockIdx.x;
    const int tid = threadIdx.x;

    // x[b] = D[doc] + sum_c W[ctx[c]]  -- 75 threads, float4 each
    if (tid < VEC_F4) {
        const int doc = doc_ids[b];
        const float4* __restrict__ Drow =
            reinterpret_cast<const float4*>(D + (size_t)doc * VEC_DIM);
        float4 v = Drow[tid];
#pragma unroll
        for (int c = 0; c < NUM_CTX; ++c) {
            const int wd = context_ids[b * NUM_CTX + c];
            const float4 u =
                reinterpret_cast<const float4*>(W + (size_t)wd * VEC_DIM)[tid];
            v.x += u.x; v.y += u.y; v.z += u.z; v.w += u.w;
        }
        xs4[tid] = v;
    }
    __syncthreads();

    const int wave = tid >> 6;
    const int lane = tid & 63;

    // Each lane keeps its two x chunks in registers across all noise words.
    const float4 xa = xs4[lane];                                  // chunks 0..63
    float4 xb = make_float4(0.f, 0.f, 0.f, 0.f);
    if (lane < VEC_F4 - 64) xb = xs4[64 + lane];                  // chunks 64..74

    const int* __restrict__ tb = tn_ids + b * NUM_NOISE;

    // 26 noise words over 4 waves; unrolled so all row loads can be hoisted (MLP).
#pragma unroll
    for (int k = 0; k < 7; ++k) {
        const int n = wave + 4 * k;
        if (n < NUM_NOISE) {
            const int t = tb[n];
            const float4* __restrict__ row =
                reinterpret_cast<const float4*>(OT + (size_t)t * VEC_DIM);
            const float4 ra = row[lane];                           // 1024 B / wave
            float s = ra.x * xa.x + ra.y * xa.y + ra.z * xa.z + ra.w * xa.w;
            if (lane < VEC_F4 - 64) {
                const float4 rb = row[64 + lane];
                s += rb.x * xb.x + rb.y * xb.y + rb.z * xb.z + rb.w * xb.w;
            }
#pragma unroll
            for (int off = 32; off > 0; off >>= 1)
                s += __shfl_down(s, off, 64);
            if (lane == 0) out[b * NUM_NOISE + n] = s;
        }
    }
}

// ---------------- Fallback (direct column gather) if ws too small ----------
__global__ __launch_bounds__(256) void pvdm_score_direct_kernel(
    const int*   __restrict__ context_ids,
    const int*   __restrict__ doc_ids,
    const int*   __restrict__ tn_ids,
    const float* __restrict__ D,
    const float* __restrict__ W,
    const float* __restrict__ O,             // (300, 100000)
    float*       __restrict__ out)
{
    __shared__ float xs[VEC_DIM];
    const int b   = blockIdx.x;
    const int tid = threadIdx.x;
    const int doc = doc_ids[b];
    int ctx[NUM_CTX];
#pragma unroll
    for (int c = 0; c < NUM_CTX; ++c) ctx[c] = context_ids[b * NUM_CTX + c];
    for (int d = tid; d < VEC_DIM; d += 256) {
        float v = D[(size_t)doc * VEC_DIM + d];
#pragma unroll
        for (int c = 0; c < NUM_CTX; ++c)
            v += W[(size_t)ctx[c] * VEC_DIM + d];
        xs[d] = v;
    }
    __syncthreads();
    const int wave = tid >> 6;
    const int lane = tid & 63;
    for (int n = wave; n < NUM_NOISE; n += 4) {
        const int t = tn_ids[b * NUM_NOISE + n];
        float s = 0.0f;
        for (int d = lane; d < VEC_DIM; d += 64)
            s += xs[d] * O[(size_t)d * NUM_WORDS + t];
#pragma unroll
        for (int off = 32; off > 0; off >>= 1)
            s += __shfl_down(s, off, 64);
        if (lane == 0) out[b * NUM_NOISE + n] = s;
    }
}

extern "C" void kernel_launch(void* const* d_in, const int* in_sizes, int n_in,
                              void* d_out, int out_size, void* d_ws, size_t ws_size,
                              hipStream_t stream) {
    const int*   context_ids = (const int*)  d_in[0];
    const int*   doc_ids     = (const int*)  d_in[1];
    const int*   tn_ids      = (const int*)  d_in[2];
    const float* D           = (const float*)d_in[3];
    const float* W           = (const float*)d_in[4];
    const float* O           = (const float*)d_in[5];
    float*       out         = (float*)d_out;

    const size_t OT_BYTES = (size_t)NUM_WORDS * VEC_DIM * sizeof(float); // 120 MB

    if (ws_size >= OT_BYTES) {
        float* OT = (float*)d_ws;
        transpose_kernel<<<NUM_WORDS / TWORDS, 256, 0, stream>>>(O, OT);
        pvdm_score_kernel<<<BATCH_N, 256, 0, stream>>>(
            context_ids, doc_ids, tn_ids, D, W, OT, out);
    } else {
        pvdm_score_direct_kernel<<<BATCH_N, 256, 0, stream>>>(
            context_ids, doc_ids, tn_ids, D, W, O, out);
    }
}